// Round 1
// baseline (750.658 us; speedup 1.0000x reference)
//
#include <hip/hip_runtime.h>
#include <stdint.h>
#include <stddef.h>

// ---------------------------------------------------------------------------
// Round 8: 256x256-tile, BK=64, 8-wave, 4-phase-per-K-tile deep pipeline
// (T2 XOR-swizzle + T3/T4 counted-vmcnt + T5 setprio), 16x16x32 MFMA.
// The R4-R7 plateau (~739 TF, MfmaUtil 30%) is the 2-barrier-per-K-step
// structure's ceiling: vmcnt(0) drains at every __syncthreads. This version
// keeps 6 global_load_lds in flight ACROSS barriers (vmcnt(6) once per
// K-tile), chunk-chasing staging 2 K-tiles ahead into the buffer being
// consumed (each chunk staged one phase after its last ds_read).
// ---------------------------------------------------------------------------

typedef __attribute__((ext_vector_type(8))) short short8;
typedef __attribute__((ext_vector_type(4))) float floatv4;
typedef __attribute__((ext_vector_type(8))) unsigned short ushort8;

#define GLOAD_LDS16(g, l)                                                      \
  __builtin_amdgcn_global_load_lds(                                            \
      (const __attribute__((address_space(1))) void*)(g),                      \
      (__attribute__((address_space(3))) void*)(l), 16, 0, 0)

__device__ __forceinline__ unsigned short f2bf(float f) {
  unsigned int u = __float_as_uint(f);
  u += 0x7fffu + ((u >> 16) & 1u);  // RNE
  return (unsigned short)(u >> 16);
}
__device__ __forceinline__ float bf2f(unsigned short s) {
  return __uint_as_float(((unsigned int)s) << 16);
}

#define NNODES 100000
#define MTOT   300000
#define HD     512
#define NH     50000
#define LSTR   264   // epilogue L row stride in shorts: 528B = 33 x 16B (odd)

// --- Wt plain panel layout: [layer][cb*8+kt][row 0..255][g 0..7][e 0..7] ----
// element = W[kt*64 + g*8 + e][cb*256 + row]   (XOR swizzle applied by the
// GEMM's staging SOURCE address, not baked here)
__global__ __launch_bounds__(256) void prep_w(const float* __restrict__ W1,
                                              const float* __restrict__ W2,
                                              const float* __restrict__ W3,
                                              unsigned short* __restrict__ Wt) {
  int t = blockIdx.x * 256 + threadIdx.x;  // < 3*512*512
  int layer = t >> 18;
  int r = t & 262143;
  int e = r & 7;
  int g = (r >> 3) & 7;
  int row = (r >> 6) & 255;
  int cbkt = r >> 14;  // 0..15
  int cb = cbkt >> 3, kt = cbkt & 7;
  int n = cb * 256 + row;
  int k = kt * 64 + g * 8 + e;
  const float* W = layer == 0 ? W1 : (layer == 1 ? W2 : W3);
  Wt[t] = f2bf(W[k * 512 + n]);
}

// --- hb = bf16(h) [50000 x 128], row-major ----------------------------------
__global__ __launch_bounds__(256) void prep_hb(const float* __restrict__ h,
                                               unsigned short* __restrict__ hb) {
  int t = blockIdx.x * 256 + threadIdx.x;  // < NH*16
  int v = t >> 4, c8 = (t & 15) * 8;
  const floatv4* hp = (const floatv4*)(h + (size_t)v * 128 + c8);
  floatv4 f0 = hp[0], f1 = hp[1];
  ushort8 o;
#pragma unroll
  for (int e = 0; e < 4; ++e) {
    o[e] = f2bf(f0[e]);
    o[4 + e] = f2bf(f1[e]);
  }
  *(ushort8*)(hb + (size_t)v * 128 + c8) = o;
}

__global__ __launch_bounds__(256) void init_out(float* __restrict__ out,
                                                const float* __restrict__ bo) {
  int t = blockIdx.x * 256 + threadIdx.x;
  if (t < 2 * NNODES) out[t] = bo[t & 1];
}

// ---------------------------------------------------------------------------
// GEMM: 256x256 tile, BK=64, K=512 (8 K-tiles), 512 thr, 16x16x32 MFMA.
// LDS: A0@0 A1@32K B0@64K B1@96K (each 32KB, row-major [256][64] bf16 with
// 16B-granule XOR (g ^ row&7) applied at source+read). Epilogue L overlays
// [0,135168); sIdx@135168 (GATHER), sWo@139264 (FINAL).
// ---------------------------------------------------------------------------

#define BAR()                            \
  __builtin_amdgcn_sched_barrier(0);     \
  __builtin_amdgcn_s_barrier();          \
  __builtin_amdgcn_sched_barrier(0)

#define STAGE_A(kk, odd)                                                       \
  {                                                                            \
    char* db = smem + ((kk) & 1) * 32768;                                      \
    _Pragma("unroll")                                                          \
    for (int qq = 0; qq < 2; ++qq) {                                           \
      int q = (odd) + qq * 2;                                                  \
      int row = q * 64 + tr;                                                   \
      const unsigned short* sp;                                                \
      if (GATHER) {                                                            \
        int srcn = sIdx[row * 4 + ((kk) >> 1)];                                \
        sp = A + (size_t)srcn * 128 + ((kk) & 1) * 64 + sxg * 8;               \
      } else {                                                                 \
        sp = A + (((size_t)(rb * 8 + (kk)) * 256 + row) * 8 + sxg) * 8;        \
      }                                                                        \
      GLOAD_LDS16(sp, db + q * 8192 + t * 16);                                 \
    }                                                                          \
  }

#define STAGE_B(kk, odd)                                                       \
  {                                                                            \
    char* db = smem + 65536 + ((kk) & 1) * 32768;                              \
    _Pragma("unroll")                                                          \
    for (int qq = 0; qq < 2; ++qq) {                                           \
      int q = (odd) + qq * 2;                                                  \
      const unsigned short* sp =                                               \
          Wt + (((size_t)(cb * 8 + (kk)) * 256 + q * 64 + tr) * 8 + sxg) * 8;  \
      GLOAD_LDS16(sp, db + q * 8192 + t * 16);                                 \
    }                                                                          \
  }

#define LDA(mh)                                                                \
  _Pragma("unroll")                                                            \
  for (int mi = 0; mi < 4; ++mi) {                                             \
    const char* rbase = bA + (wmbase + (mh) * 64 + mi * 16 + lr) * 128;        \
    a[mi][0] = *(const short8*)(rbase + xb0);                                  \
    a[mi][1] = *(const short8*)(rbase + xb1);                                  \
  }

#define LDB(nh)                                                                \
  _Pragma("unroll")                                                            \
  for (int nj = 0; nj < 2; ++nj) {                                             \
    const char* rbase = bB + (wnbase + (nh) * 32 + nj * 16 + lr) * 128;        \
    b[(nh) * 2 + nj][0] = *(const short8*)(rbase + xb0);                       \
    b[(nh) * 2 + nj][1] = *(const short8*)(rbase + xb1);                       \
  }

#define MMA(mh, nh)                                                            \
  __builtin_amdgcn_s_setprio(1);                                               \
  _Pragma("unroll")                                                            \
  for (int mi = 0; mi < 4; ++mi)                                               \
    _Pragma("unroll")                                                          \
    for (int nj = 0; nj < 2; ++nj) {                                           \
      acc[(mh) * 4 + mi][(nh) * 2 + nj] =                                      \
          __builtin_amdgcn_mfma_f32_16x16x32_bf16(                             \
              a[mi][0], b[(nh) * 2 + nj][0],                                   \
              acc[(mh) * 4 + mi][(nh) * 2 + nj], 0, 0, 0);                     \
      acc[(mh) * 4 + mi][(nh) * 2 + nj] =                                      \
          __builtin_amdgcn_mfma_f32_16x16x32_bf16(                             \
              a[mi][1], b[(nh) * 2 + nj][1],                                   \
              acc[(mh) * 4 + mi][(nh) * 2 + nj], 0, 0, 0);                     \
    }                                                                          \
  __builtin_amdgcn_s_setprio(0);

template <int GATHER, int FINAL>
__global__ __launch_bounds__(512, 2) void gemm_k(
    const unsigned short* __restrict__ A,   // GATHER ? hb(row-major) : X panel
    const int* __restrict__ idx,
    const unsigned short* __restrict__ Wt,  // plain panel layout
    const float* __restrict__ bias,
    unsigned short* __restrict__ Xout,      // plain panel layout
    float* __restrict__ out, const float* __restrict__ Wo,
    int mchunk0) {
  __shared__ __align__(16) char smem[141312];
  int* sIdx = (int*)(smem + 135168);
  float* sWo = (float*)(smem + 139264);

  const int t = threadIdx.x;
  int bx = blockIdx.x;
  // XCD swizzle (grid is a multiple of 48, hence of 8); the 2 col-blocks of
  // one row-block are adjacent -> same XCD chunk (shared A panel in L2).
  int cpx = (int)gridDim.x >> 3;
  int wg = (bx & 7) * cpx + (bx >> 3);
  int cb = wg & 1;
  int rb = wg >> 1;
  int n0 = cb * 256;

  const int l = t & 63;
  const int w = t >> 6;
  const int wmbase = (w >> 2) * 128;  // 2 warp-rows
  const int wnbase = (w & 3) * 64;    // 4 warp-cols
  const int lr = l & 15, lk = l >> 4;
  const int xb0 = (lk ^ (lr & 7)) * 16;  // ks=0 granule byte (XOR swizzle)
  const int xb1 = xb0 ^ 64;              // ks=1: granule ^= 4
  const int tr = t >> 3;                 // staging row-in-quarter
  const int sxg = (t & 7) ^ (tr & 7);    // staging source granule (inverse XOR)

  if (FINAL) sWo[t] = Wo[n0 * 2 + t];
  if (GATHER) {
    if (t < 256) {
      int m = mchunk0 + rb * 256 + t;
      unsigned um = (unsigned)m;
      unsigned n = um / 3u;
      int p = (int)(um - n * 3u);
      if (n >= (unsigned)NNODES) n = 0;  // padded tail: junk, guarded at out
      const unsigned pk0 = 0x320u, pk1 = 0x111u, pk2 = 0x032u, pk3 = 0x203u;
      int sh = p * 4;
      sIdx[t * 4 + 0] = idx[n * 4 + ((pk0 >> sh) & 0xFu)];
      sIdx[t * 4 + 1] = idx[n * 4 + ((pk1 >> sh) & 0xFu)];
      sIdx[t * 4 + 2] = idx[n * 4 + ((pk2 >> sh) & 0xFu)];
      sIdx[t * 4 + 3] = idx[n * 4 + ((pk3 >> sh) & 0xFu)];
    }
    __syncthreads();
  }

  floatv4 acc[8][4];
#pragma unroll
  for (int i = 0; i < 8; ++i)
#pragma unroll
    for (int j = 0; j < 4; ++j)
#pragma unroll
      for (int r = 0; r < 4; ++r) acc[i][j][r] = 0.f;

  // Prologue: K-tile0 fully (8 loads/thr) + K-tile1 {A-even,B-even,B-odd} (6).
  // vmcnt(6) completes exactly K-tile0; the 6 K-tile1 loads stay in flight.
  STAGE_A(0, 0); STAGE_A(0, 1); STAGE_B(0, 0); STAGE_B(0, 1);
  STAGE_A(1, 0); STAGE_B(1, 0); STAGE_B(1, 1);
  asm volatile("s_waitcnt vmcnt(6)" ::: "memory");
  BAR();

  // Main loop. Ledger (per-thread, 2 loads/chunk): vmcnt(6) at p4 of K-tile k
  // completes {A-even,B-even,B-odd,A-odd} of k+1, leaves k+2's first 3 chunks
  // (6 loads) in flight. Chunks staged into the CONSUMED buffer one phase
  // after their region's last ds_read (A-even read@p1 -> staged@p2, etc).
#pragma unroll 2
  for (int k = 0; k < 8; ++k) {
    const char* bA = smem + (k & 1) * 32768;
    const char* bB = smem + 65536 + (k & 1) * 32768;
    short8 a[4][2], b[4][2];
    // ---- phase 1: quad (0,0); stage A-odd(k+1) into other buffer
    LDA(0);
    LDB(0);
    if (k < 7) STAGE_A(k + 1, 1);
    BAR();
    MMA(0, 0);
    BAR();
    // ---- phase 2: quad (0,1); stage A-even(k+2) (A-even(k) consumed @p1)
    LDB(1);
    if (k < 6) STAGE_A(k + 2, 0);
    BAR();
    MMA(0, 1);
    BAR();
    // ---- phase 3: quad (1,0); stage B-even(k+2) (all B consumed by p2)
    LDA(1);
    if (k < 6) STAGE_B(k + 2, 0);
    BAR();
    MMA(1, 0);
    BAR();
    // ---- phase 4: quad (1,1); stage B-odd(k+2); counted drain
    if (k < 6) STAGE_B(k + 2, 1);
    BAR();
    MMA(1, 1);
    if (k < 6) {
      asm volatile("s_waitcnt vmcnt(6)" ::: "memory");
    } else {
      asm volatile("s_waitcnt vmcnt(0)" ::: "memory");
    }
    BAR();
  }

  // Epilogue. 16x16 C/D: col = lane&15, row = (lane>>4)*4 + reg.
  unsigned short* L = (unsigned short*)smem;
  {
    float bv[4];
#pragma unroll
    for (int nj = 0; nj < 4; ++nj) bv[nj] = bias[n0 + wnbase + nj * 16 + lr];
#pragma unroll
    for (int mi = 0; mi < 8; ++mi)
#pragma unroll
      for (int nj = 0; nj < 4; ++nj) {
        int col = wnbase + nj * 16 + lr;
#pragma unroll
        for (int r = 0; r < 4; ++r) {
          int row = wmbase + mi * 16 + lk * 4 + r;
          float v = fmaxf(acc[mi][nj][r] + bv[nj], 0.f);
          L[row * LSTR + col] = f2bf(v);
        }
      }
  }
  __syncthreads();

  if (!FINAL) {
    // plain panel-order stores: consecutive t -> consecutive 16B slots
#pragma unroll
    for (int it = 0; it < 16; ++it) {
      int slot = it * 512 + t;  // 0..8191
      int ktq = slot >> 11;     // local k-tile 0..3
      int s = slot & 2047;
      int row = s >> 3, g = s & 7;
      ushort8 val = *(const ushort8*)(L + row * LSTR + ktq * 64 + g * 8);
      *(ushort8*)(Xout +
                  ((size_t)((rb * 8 + cb * 4 + ktq) * 256 + row) * 8 + g) * 8) =
          val;
    }
  } else {
    int r2 = t >> 1, jo = t & 1;
    int grow = mchunk0 + rb * 256 + r2;
    if (grow < MTOT) {
      const unsigned short* Lr = L + r2 * LSTR;
      float s = 0.f;
#pragma unroll
      for (int cc = 0; cc < 256; cc += 2) {
        unsigned int pair = *(const unsigned int*)(Lr + cc);
        s += bf2f((unsigned short)(pair & 0xffffu)) * sWo[2 * cc + jo];
        s += bf2f((unsigned short)(pair >> 16)) * sWo[2 * cc + 2 + jo];
      }
      int node = grow / 3;
      atomicAdd(out + node * 2 + jo, s);
    }
  }
}

extern "C" void kernel_launch(void* const* d_in, const int* in_sizes, int n_in,
                              void* d_out, int out_size, void* d_ws,
                              size_t ws_size, hipStream_t stream) {
  const float* h  = (const float*)d_in[0];
  const int*   ix = (const int*)d_in[1];
  const float* W1 = (const float*)d_in[2];
  const float* b1 = (const float*)d_in[3];
  const float* W2 = (const float*)d_in[4];
  const float* b2 = (const float*)d_in[5];
  const float* W3 = (const float*)d_in[6];
  const float* b3 = (const float*)d_in[7];
  const float* Wo = (const float*)d_in[8];
  const float* bo = (const float*)d_in[9];
  float* out = (float*)d_out;

  unsigned short* ws = (unsigned short*)d_ws;
  unsigned short* Wt = ws;                  // 3*512*512 shorts (panel)
  unsigned short* hb = Wt + 786432;         // 50000*128 shorts (row-major)
  unsigned short* bufs = hb + 6400000;
  const size_t baseBytes = (786432ull + 6400000ull) * 2;

  // nodes per chunk: multiple of 2048 -> rows%6144==0 -> RB%24==0, grid%48==0
  size_t avail = ws_size > baseBytes ? ws_size - baseBytes : 0;
  size_t ncap = avail / (2ull * 3 * HD * sizeof(unsigned short));
  size_t nc = (ncap / 2048) * 2048;
  if (nc > 32768) nc = 32768;
  if (nc == 0) nc = 2048;  // best effort
  unsigned short* X1 = bufs;                // panel layout
  unsigned short* X2 = X1 + nc * 3 * HD;    // panel layout

  prep_w<<<3072, 256, 0, stream>>>(W1, W2, W3, Wt);
  prep_hb<<<NH * 16 / 256, 256, 0, stream>>>(h, hb);
  init_out<<<(2 * NNODES + 255) / 256, 256, 0, stream>>>(out, bo);

  for (size_t n0c = 0; n0c < NNODES; n0c += nc) {
    size_t remn = (size_t)NNODES - n0c;
    size_t ncp = remn < nc ? ((remn + 2047) / 2048) * 2048 : nc;
    int rows = (int)(ncp * 3);
    int RB = rows / 256;
    int m0 = (int)(3 * n0c);
    gemm_k<1, 0><<<RB * 2, 512, 0, stream>>>(hb, ix, Wt, b1, X1, nullptr,
                                             nullptr, m0);
    gemm_k<0, 0><<<RB * 2, 512, 0, stream>>>(X1, nullptr, Wt + 262144, b2, X2,
                                             nullptr, nullptr, m0);
    gemm_k<0, 1><<<RB * 2, 512, 0, stream>>>(X2, nullptr, Wt + 524288, b3,
                                             nullptr, out, Wo, m0);
  }
}